// Round 1
// baseline (10933.286 us; speedup 1.0000x reference)
//
#include <hip/hip_runtime.h>
#include <hip/hip_bf16.h>
#include <math.h>

#define B_   16
#define CIN  32
#define COUT 64
#define H0   128
#define W0   256
#define H1   130
#define W1   258
#define H2   132
#define W2   260
#define N1   (H1*W1)   /* 33540 */
#define N2   (H2*W2)   /* 34320 */
#define PH   44
#define PW   86
#define EPS  1e-5f

typedef __hip_bfloat16 bf16;

__global__ void zero_kernel(float* __restrict__ p, int n) {
    int i = blockIdx.x*blockDim.x + threadIdx.x;
    if (i < n) p[i] = 0.f;
}

// cw[r,i,j] = softmax_r(ah[r,i] + aw[r,j]); stored as [4][Lh*Lw]
__global__ void cw_kernel(const float* __restrict__ ah, const float* __restrict__ aw,
                          float* __restrict__ cw, int Lh, int Lw) {
    int idx = blockIdx.x*blockDim.x + threadIdx.x;
    int n = Lh*Lw;
    if (idx >= n) return;
    int i = idx / Lw, j = idx - i*Lw;
    float v0 = ah[0*Lh+i] + aw[0*Lw+j];
    float v1 = ah[1*Lh+i] + aw[1*Lw+j];
    float v2 = ah[2*Lh+i] + aw[2*Lw+j];
    float v3 = ah[3*Lh+i] + aw[3*Lw+j];
    float m = fmaxf(fmaxf(v0,v1), fmaxf(v2,v3));
    v0 = __expf(v0-m); v1 = __expf(v1-m); v2 = __expf(v2-m); v3 = __expf(v3-m);
    float inv = 1.f/(v0+v1+v2+v3);
    cw[0*n+idx] = v0*inv; cw[1*n+idx] = v1*inv;
    cw[2*n+idx] = v2*inv; cw[3*n+idx] = v3*inv;
}

// Layer 1: direct conv, 4 rank accumulators per thread, combine + bias fused.
// grid: (ceil(N1/256), COUT, B_), block 256. Weights for this co staged in LDS.
__launch_bounds__(256)
__global__ void conv1_kernel(const float* __restrict__ x, const float* __restrict__ w1,
                             const float* __restrict__ b1, const float* __restrict__ cw,
                             bf16* __restrict__ h1) {
    __shared__ float lw[CIN*9*4];          // [ci][tap][r]
    const int co = blockIdx.y;
    const int b  = blockIdx.z;
    for (int idx = threadIdx.x; idx < CIN*9*4; idx += 256) {
        int r = idx & 3, ck = idx >> 2;
        int ci = ck / 9, t = ck - ci*9;
        lw[idx] = w1[(((r*COUT + co)*CIN + ci)*9) + t];
    }
    __syncthreads();
    int p = blockIdx.x*256 + threadIdx.x;
    if (p >= N1) return;
    int oh = p / W1, ow = p - oh*W1;
    float a0=0.f, a1=0.f, a2=0.f, a3=0.f;
    const float* xb = x + (size_t)b*CIN*H0*W0;
    for (int ci = 0; ci < CIN; ++ci) {
        const float* xc  = xb + ci*(H0*W0);
        const float* lwc = lw + ci*36;
        #pragma unroll
        for (int kh = 0; kh < 3; ++kh) {
            int ih = oh + kh - 2;
            if ((unsigned)ih < (unsigned)H0) {
                const float* xr = xc + ih*W0;
                #pragma unroll
                for (int kw = 0; kw < 3; ++kw) {
                    int iw = ow + kw - 2;
                    float xv = ((unsigned)iw < (unsigned)W0) ? xr[iw] : 0.f;
                    const float* wp = lwc + (kh*3+kw)*4;
                    a0 = fmaf(xv, wp[0], a0);
                    a1 = fmaf(xv, wp[1], a1);
                    a2 = fmaf(xv, wp[2], a2);
                    a3 = fmaf(xv, wp[3], a3);
                }
            }
        }
    }
    float out = a0*cw[p] + a1*cw[N1+p] + a2*cw[2*N1+p] + a3*cw[3*N1+p] + b1[co];
    h1[(size_t)(b*COUT+co)*N1 + p] = __float2bfloat16(out);
}

// Layer 2: same, Cin=64, input is bf16 (already BN+ReLU normalized in place).
__launch_bounds__(256)
__global__ void conv2_kernel(const bf16* __restrict__ h1, const float* __restrict__ w2,
                             const float* __restrict__ b2, const float* __restrict__ cw,
                             bf16* __restrict__ h2) {
    __shared__ float lw[COUT*9*4];         // 2304 floats
    const int co = blockIdx.y;
    const int b  = blockIdx.z;
    for (int idx = threadIdx.x; idx < COUT*9*4; idx += 256) {
        int r = idx & 3, ck = idx >> 2;
        int ci = ck / 9, t = ck - ci*9;
        lw[idx] = w2[(((r*COUT + co)*COUT + ci)*9) + t];
    }
    __syncthreads();
    int p = blockIdx.x*256 + threadIdx.x;
    if (p >= N2) return;
    int oh = p / W2, ow = p - oh*W2;
    float a0=0.f, a1=0.f, a2=0.f, a3=0.f;
    const bf16* xb = h1 + (size_t)b*COUT*N1;
    for (int ci = 0; ci < COUT; ++ci) {
        const bf16* xc   = xb + (size_t)ci*N1;
        const float* lwc = lw + ci*36;
        #pragma unroll
        for (int kh = 0; kh < 3; ++kh) {
            int ih = oh + kh - 2;
            if ((unsigned)ih < (unsigned)H1) {
                const bf16* xr = xc + ih*W1;
                #pragma unroll
                for (int kw = 0; kw < 3; ++kw) {
                    int iw = ow + kw - 2;
                    float xv = ((unsigned)iw < (unsigned)W1) ? __bfloat162float(xr[iw]) : 0.f;
                    const float* wp = lwc + (kh*3+kw)*4;
                    a0 = fmaf(xv, wp[0], a0);
                    a1 = fmaf(xv, wp[1], a1);
                    a2 = fmaf(xv, wp[2], a2);
                    a3 = fmaf(xv, wp[3], a3);
                }
            }
        }
    }
    float out = a0*cw[p] + a1*cw[N2+p] + a2*cw[2*N2+p] + a3*cw[3*N2+p] + b2[co];
    h2[(size_t)(b*COUT+co)*N2 + p] = __float2bfloat16(out);
}

// Per-channel sum / sumsq over [B, n] planes. grid (128, COUT), block 256.
__global__ void stats_kernel(const bf16* __restrict__ h, float* __restrict__ sum,
                             float* __restrict__ sumsq, int n, int nb) {
    int co = blockIdx.y;
    float s = 0.f, s2 = 0.f;
    for (int b = 0; b < nb; ++b) {
        const bf16* hp = h + (size_t)(b*COUT + co)*n;
        for (int p = blockIdx.x*blockDim.x + threadIdx.x; p < n; p += gridDim.x*blockDim.x) {
            float v = __bfloat162float(hp[p]);
            s += v;
            s2 = fmaf(v, v, s2);
        }
    }
    for (int off = 32; off > 0; off >>= 1) {
        s  += __shfl_down(s,  off, 64);
        s2 += __shfl_down(s2, off, 64);
    }
    __shared__ float ls[4], ls2[4];
    int wid = threadIdx.x >> 6, lane = threadIdx.x & 63;
    if (lane == 0) { ls[wid] = s; ls2[wid] = s2; }
    __syncthreads();
    if (threadIdx.x == 0) {
        float ts = 0.f, t2 = 0.f;
        for (int i = 0; i < 4; ++i) { ts += ls[i]; t2 += ls2[i]; }
        atomicAdd(&sum[co], ts);
        atomicAdd(&sumsq[co], t2);
    }
}

// A = g*rsqrt(var+eps); Bc = be - mean*A
__global__ void finalize_kernel(const float* __restrict__ sum, const float* __restrict__ sumsq,
                                const float* __restrict__ g, const float* __restrict__ be,
                                float* __restrict__ A, float* __restrict__ Bc, float cnt) {
    int c = threadIdx.x;
    if (c >= COUT) return;
    float mean = sum[c]/cnt;
    float var  = sumsq[c]/cnt - mean*mean;
    float inv  = rsqrtf(var + EPS);
    float a = g[c]*inv;
    A[c]  = a;
    Bc[c] = fmaf(-mean, a, be[c]);
}

// In-place BN+ReLU on bf16 plane buffer. grid (ceil(n/256), B_*COUT)
__global__ void bnrelu_kernel(bf16* __restrict__ h, const float* __restrict__ A,
                              const float* __restrict__ Bc, int n) {
    int c = blockIdx.y & (COUT-1);
    float a = A[c], bc = Bc[c];
    bf16* hp = h + (size_t)blockIdx.y*n;
    int p = blockIdx.x*blockDim.x + threadIdx.x;
    if (p < n) {
        float v = __bfloat162float(hp[p]);
        v = fmaxf(fmaf(v, a, bc), 0.f);
        hp[p] = __float2bfloat16(v);
    }
}

// Fused BN2 + ReLU + 3x3/3 maxpool -> fp32 out [16,64,44,86]
__global__ void maxpool_kernel(const bf16* __restrict__ h2, const float* __restrict__ A,
                               const float* __restrict__ Bc, float* __restrict__ out) {
    int idx = blockIdx.x*blockDim.x + threadIdx.x;
    int total = B_*COUT*PH*PW;
    if (idx >= total) return;
    int ow = idx % PW; int t = idx / PW;
    int oh = t % PH;   t /= PH;
    int c  = t % COUT; int b = t / COUT;
    const bf16* hp = h2 + (size_t)(b*COUT + c)*N2 + (oh*3)*W2 + ow*3;
    float a = A[c], bc = Bc[c];
    float m = 0.f;   // == relu floor; max(relu(v)) = max(0, max(affine v))
    #pragma unroll
    for (int i = 0; i < 3; ++i)
        #pragma unroll
        for (int j = 0; j < 3; ++j) {
            float v = fmaf(__bfloat162float(hp[i*W2 + j]), a, bc);
            m = fmaxf(m, v);
        }
    out[idx] = m;
}

extern "C" void kernel_launch(void* const* d_in, const int* in_sizes, int n_in,
                              void* d_out, int out_size, void* d_ws, size_t ws_size,
                              hipStream_t stream) {
    const float* x   = (const float*)d_in[0];
    const float* w1  = (const float*)d_in[1];
    const float* b1  = (const float*)d_in[2];
    const float* a1h = (const float*)d_in[3];
    const float* a1w = (const float*)d_in[4];
    const float* g1  = (const float*)d_in[5];
    const float* be1 = (const float*)d_in[6];
    const float* w2  = (const float*)d_in[7];
    const float* b2  = (const float*)d_in[8];
    const float* a2h = (const float*)d_in[9];
    const float* a2w = (const float*)d_in[10];
    const float* g2  = (const float*)d_in[11];
    const float* be2 = (const float*)d_in[12];
    float* out = (float*)d_out;

    char* ws = (char*)d_ws;
    // ws layout: [512 floats stats][cw1 4*N1 f32][cw2 4*N2 f32][h1 bf16][h2 bf16]
    float* stats = (float*)ws;
    float* sum1 = stats;       float* sq1 = stats + 64;
    float* A1   = stats + 128; float* Bc1 = stats + 192;
    float* sum2 = stats + 256; float* sq2 = stats + 320;
    float* A2   = stats + 384; float* Bc2 = stats + 448;
    float* cw1 = (float*)(ws + 2048);
    float* cw2 = cw1 + 4*N1;
    bf16*  h1  = (bf16*)(cw2 + 4*N2);
    bf16*  h2  = h1 + (size_t)B_*COUT*N1;
    // total ws use: 2048 + 536640 + 549120 + 68689920 + 70287360 ≈ 134 MiB

    zero_kernel<<<2, 256, 0, stream>>>(stats, 512);
    cw_kernel<<<(N1+255)/256, 256, 0, stream>>>(a1h, a1w, cw1, H1, W1);
    cw_kernel<<<(N2+255)/256, 256, 0, stream>>>(a2h, a2w, cw2, H2, W2);

    conv1_kernel<<<dim3((N1+255)/256, COUT, B_), 256, 0, stream>>>(x, w1, b1, cw1, h1);
    stats_kernel<<<dim3(128, COUT), 256, 0, stream>>>(h1, sum1, sq1, N1, B_);
    finalize_kernel<<<1, 64, 0, stream>>>(sum1, sq1, g1, be1, A1, Bc1, (float)(B_*N1));
    bnrelu_kernel<<<dim3((N1+255)/256, B_*COUT), 256, 0, stream>>>(h1, A1, Bc1, N1);

    conv2_kernel<<<dim3((N2+255)/256, COUT, B_), 256, 0, stream>>>(h1, w2, b2, cw2, h2);
    stats_kernel<<<dim3(128, COUT), 256, 0, stream>>>(h2, sum2, sq2, N2, B_);
    finalize_kernel<<<1, 64, 0, stream>>>(sum2, sq2, g2, be2, A2, Bc2, (float)(B_*N2));

    maxpool_kernel<<<(B_*COUT*PH*PW+255)/256, 256, 0, stream>>>(h2, A2, Bc2, out);
}

// Round 3
// 1348.703 us; speedup vs baseline: 8.1065x; 8.1065x over previous
//
#include <hip/hip_runtime.h>
#include <hip/hip_bf16.h>
#include <math.h>

#define COUT 64
#define EPS  1e-5f

typedef __hip_bfloat16 bf16;
typedef short  short8  __attribute__((ext_vector_type(8)));
typedef short  short4v __attribute__((ext_vector_type(4)));
typedef float  floatx4 __attribute__((ext_vector_type(4)));

__device__ __forceinline__ short bf16_bits(float f) {
    union { __hip_bfloat16 h; short s; } u;
    u.h = __float2bfloat16(f);
    return u.s;
}
__device__ __forceinline__ float bits_to_f32(short s) {
    union { __hip_bfloat16 h; short s; } u;
    u.s = s;
    return __bfloat162float(u.h);
}

// ---------------- geometry ----------------
// conv1: input x fp32 NCHW [16][32][128][256] -> xpad bf16 NHWC [16][132][260][32]
//        virtual out plane: 130 rows x 260 (valid ow<258), Nv1=33800
//        writes h1pad interior: [16][134][262][64], pad=2
// conv2: input h1pad (bn+relu'd), virtual out 132 x 262 (valid ow<260), Nv2=34584
//        writes h2 NHWC [16][132][260][64]
#define NV1   33800
#define NV2   34584
#define XPAD_PLANE  (132*260)      /* 34320 */
#define H1_PLANE    (134*262)      /* 35108 */
#define H2_PLANE    (132*260)      /* 34320 */
#define NPOS1 (16*130*258)         /* 536640 */
#define NPOS2 (16*132*260)         /* 549120 */

// ---------------- tiny utils ----------------
__global__ void zero_f_kernel(float* __restrict__ p, int n) {
    int i = blockIdx.x*blockDim.x + threadIdx.x;
    if (i < n) p[i] = 0.f;
}
__global__ void zero4_kernel(uint4* __restrict__ p, long n4) {
    long i = (long)blockIdx.x*blockDim.x + threadIdx.x;
    for (; i < n4; i += (long)gridDim.x*blockDim.x) p[i] = make_uint4(0,0,0,0);
}

// combining weights on the virtual plane: cwv[r][Nv]
__global__ void cwv_kernel(const float* __restrict__ ah, const float* __restrict__ aw,
                           float* __restrict__ cwv, int Nv, int Wv, int Lh, int Lw) {
    int idx = blockIdx.x*blockDim.x + threadIdx.x;
    if (idx >= Nv) return;
    int oh = idx / Wv, ow = idx - oh*Wv;
    if (ow > Lw-1) ow = Lw-1;                 // garbage cols: clamp (masked at store)
    float v0 = ah[0*Lh+oh] + aw[0*Lw+ow];
    float v1 = ah[1*Lh+oh] + aw[1*Lw+ow];
    float v2 = ah[2*Lh+oh] + aw[2*Lw+ow];
    float v3 = ah[3*Lh+oh] + aw[3*Lw+ow];
    float m = fmaxf(fmaxf(v0,v1), fmaxf(v2,v3));
    v0 = __expf(v0-m); v1 = __expf(v1-m); v2 = __expf(v2-m); v3 = __expf(v3-m);
    float inv = 1.f/(v0+v1+v2+v3);
    cwv[0*(size_t)Nv+idx] = v0*inv; cwv[1*(size_t)Nv+idx] = v1*inv;
    cwv[2*(size_t)Nv+idx] = v2*inv; cwv[3*(size_t)Nv+idx] = v3*inv;
}

// pack weights [4][64][CIN][3][3] fp32 -> fragment-major bf16:
// Apk[((s*16+t)*64+l)*8+j] = A[m=t*16+(l&15)][k=s*32+(l>>4)*8+j],  k = tap*CIN + ci
template<int CIN_, int NSLICES>
__global__ void pack_kernel(const float* __restrict__ w, short* __restrict__ Apk) {
    int gid = blockIdx.x*256 + threadIdx.x;
    if (gid >= NSLICES*1024) return;
    int l = gid & 63, t = (gid >> 6) & 15, s = gid >> 10;
    int m = t*16 + (l & 15);
    int r = m >> 6, co = m & 63;
    int kbase = s*32 + ((l >> 4) << 3);
    short8 v;
    #pragma unroll
    for (int j = 0; j < 8; ++j) {
        int k = kbase + j;
        int tap = k / CIN_, ci = k % CIN_;
        float f = w[(((size_t)(r*COUT + co))*CIN_ + ci)*9 + tap];
        v[j] = bf16_bits(f);
    }
    *reinterpret_cast<short8*>(Apk + (size_t)gid*8) = v;
}

// x fp32 NCHW -> xpad bf16 NHWC [16][132][260][32], zero pads. block per (b,ih).
__global__ void xpad_kernel(const float* __restrict__ x, short* __restrict__ xp) {
    int row = blockIdx.x;                 // b*132 + ih
    int b = row / 132, ih = row - b*132;
    int ci = threadIdx.x & 31, iw0 = threadIdx.x >> 5;
    for (int iw = iw0; iw < 260; iw += 8) {
        float v = 0.f;
        if (ih >= 2 && ih < 130 && iw >= 2 && iw < 258)
            v = x[(((size_t)b*32 + ci)*128 + (ih-2))*256 + (iw-2)];
        xp[((size_t)row*260 + iw)*32 + ci] = bf16_bits(v);
    }
}

// ---------------- the MFMA implicit-GEMM LRLC conv ----------------
// block: 256 thr = 4 waves. M=256 (4 ranks x 64 co), N=64 virtual positions.
// wave w owns m-tiles {i*4+w}: frag-row i == rank i, co in [w*16, w*16+16).
// B-frag lane l: n = n0+j*16+(l&15), k = cb+(l>>4)*8.. -> contiguous 16B in NHWC.
template<int CIN_, int NSLICES>
__launch_bounds__(256, 2)
__global__ void lrlc_conv(const short* __restrict__ Bpl, const short* __restrict__ Apk,
                          const float* __restrict__ cwv, const float* __restrict__ bias,
                          short* __restrict__ Out,
                          int Wv, int Hout, int Wreal, int Nv, int inPlanePos,
                          int outW, int outPlanePos, int outPad) {
    const int tid  = threadIdx.x;
    const int w    = tid >> 6, l = tid & 63;
    const int quad = l >> 4, l15 = l & 15;
    const int b    = blockIdx.y;
    const int n0   = blockIdx.x * 64;

    __shared__ float cwS[4*64];
    {
        int r = tid >> 6, nn = tid & 63;
        int n = n0 + nn; if (n > Nv-1) n = Nv-1;
        cwS[r*64 + nn] = cwv[(size_t)r*Nv + n];
    }
    __syncthreads();

    const short* Bb = Bpl + (size_t)b*inPlanePos*CIN_;
    int bOff[4];
    #pragma unroll
    for (int j = 0; j < 4; ++j) bOff[j] = (n0 + j*16 + l15)*CIN_ + quad*8;
    const short* Aw = Apk + (size_t)(w*64 + l)*8;

    floatx4 acc[4][4];
    #pragma unroll
    for (int i = 0; i < 4; ++i)
        #pragma unroll
        for (int j = 0; j < 4; ++j)
            acc[i][j] = (floatx4){0.f,0.f,0.f,0.f};

    for (int s = 0; s < NSLICES; ++s) {
        const int tap = (CIN_ == 32) ? s : (s >> 1);
        const int cb  = (CIN_ == 32) ? 0 : ((s & 1) << 5);
        const int koff = ((tap/3)*Wv + (tap%3))*CIN_ + cb;
        short8 bfr[4], afr[4];
        #pragma unroll
        for (int j = 0; j < 4; ++j)
            bfr[j] = *reinterpret_cast<const short8*>(Bb + bOff[j] + koff);
        #pragma unroll
        for (int i = 0; i < 4; ++i)
            afr[i] = *reinterpret_cast<const short8*>(Aw + (size_t)(s*16 + i*4)*512);
        #pragma unroll
        for (int i = 0; i < 4; ++i)
            #pragma unroll
            for (int j = 0; j < 4; ++j)
                acc[i][j] = __builtin_amdgcn_mfma_f32_16x16x32_bf16(afr[i], bfr[j], acc[i][j], 0, 0, 0);
    }

    // epilogue: rank-combine in registers, + bias, store bf16x4 (8B) per (j)
    const int co_base = w*16 + quad*4;
    float bs[4];
    #pragma unroll
    for (int rg = 0; rg < 4; ++rg) bs[rg] = bias[co_base + rg];
    #pragma unroll
    for (int j = 0; j < 4; ++j) {
        int nl = j*16 + l15;
        int n  = n0 + nl;
        int oh = n / Wv, ow = n - oh*Wv;
        if (ow >= Wreal || oh >= Hout) continue;
        float c0 = cwS[nl], c1 = cwS[64+nl], c2 = cwS[128+nl], c3 = cwS[192+nl];
        short4v pk;
        #pragma unroll
        for (int rg = 0; rg < 4; ++rg) {
            float v = acc[0][j][rg]*c0 + acc[1][j][rg]*c1
                    + acc[2][j][rg]*c2 + acc[3][j][rg]*c3 + bs[rg];
            pk[rg] = bf16_bits(v);
        }
        size_t op = ((size_t)b*outPlanePos + (size_t)(oh + outPad)*outW + (ow + outPad))*(size_t)COUT + co_base;
        *reinterpret_cast<short4v*>(Out + op) = pk;
    }
}

// per-channel sum/sumsq over valid region of NHWC (C=64) buffer
__global__ void stats_nhwc(const short* __restrict__ h, float* __restrict__ sum,
                           float* __restrict__ sq, int npos, int Wreal, int Hreal,
                           int rowW, int planePos, int pad) {
    int c = threadIdx.x & 63, sub = threadIdx.x >> 6;
    float s = 0.f, s2 = 0.f;
    for (long p = blockIdx.x*4 + sub; p < npos; p += (long)gridDim.x*4) {
        int ow = (int)(p % Wreal); long t2 = p / Wreal;
        int oh = (int)(t2 % Hreal); int b = (int)(t2 / Hreal);
        float v = bits_to_f32(h[((size_t)b*planePos + (size_t)(oh+pad)*rowW + ow + pad)*64 + c]);
        s += v; s2 = fmaf(v, v, s2);
    }
    __shared__ float ls[4][64], ls2[4][64];
    ls[sub][c] = s; ls2[sub][c] = s2;
    __syncthreads();
    if (threadIdx.x < 64) {
        float ts  = ls[0][c]+ls[1][c]+ls[2][c]+ls[3][c];
        float ts2 = ls2[0][c]+ls2[1][c]+ls2[2][c]+ls2[3][c];
        atomicAdd(&sum[c], ts);
        atomicAdd(&sq[c], ts2);
    }
}

__global__ void finalize_kernel(const float* __restrict__ sum, const float* __restrict__ sumsq,
                                const float* __restrict__ g, const float* __restrict__ be,
                                float* __restrict__ A, float* __restrict__ Bc, float cnt) {
    int c = threadIdx.x;
    if (c >= COUT) return;
    float mean = sum[c]/cnt;
    float var  = sumsq[c]/cnt - mean*mean;
    float inv  = rsqrtf(var + EPS);
    float a = g[c]*inv;
    A[c]  = a;
    Bc[c] = fmaf(-mean, a, be[c]);
}

// in-place BN+ReLU on interior of NHWC buffer, 4 channels per thread
__global__ void bnrelu_nhwc(short* __restrict__ h, const float* __restrict__ A,
                            const float* __restrict__ Bc, int npos, int Wreal, int Hreal,
                            int rowW, int planePos, int pad) {
    __shared__ float sA[64], sB[64];
    if (threadIdx.x < 64) { sA[threadIdx.x] = A[threadIdx.x]; sB[threadIdx.x] = Bc[threadIdx.x]; }
    __syncthreads();
    long g = (long)blockIdx.x*256 + threadIdx.x;
    if (g >= (long)npos*16) return;
    int cg = (int)(g & 15); long p = g >> 4;
    int ow = (int)(p % Wreal); long t2 = p / Wreal;
    int oh = (int)(t2 % Hreal); int b = (int)(t2 / Hreal);
    size_t base = ((size_t)b*planePos + (size_t)(oh+pad)*rowW + ow + pad)*64 + cg*4;
    short4v d = *reinterpret_cast<short4v*>(h + base);
    #pragma unroll
    for (int q = 0; q < 4; ++q) {
        float v = bits_to_f32(d[q]);
        int c = cg*4 + q;
        v = fmaxf(fmaf(v, sA[c], sB[c]), 0.f);
        d[q] = bf16_bits(v);
    }
    *reinterpret_cast<short4v*>(h + base) = d;
}

// fused BN2+ReLU+3x3/3 maxpool: h2 NHWC -> out fp32 NCHW [16,64,44,86]
__global__ void maxpool_nhwc(const short* __restrict__ h2, const float* __restrict__ A,
                             const float* __restrict__ Bc, float* __restrict__ out) {
    int idx = blockIdx.x*blockDim.x + threadIdx.x;
    const int total = 16*64*44*86;
    if (idx >= total) return;
    int pw = idx % 86; int t = idx / 86;
    int ph = t % 44;   t /= 44;
    int c  = t % 64;   int b = t / 64;
    float a = A[c], bc = Bc[c];
    float m = 0.f;    // ReLU floor
    #pragma unroll
    for (int i = 0; i < 3; ++i) {
        size_t rbase = ((size_t)(b*132 + ph*3 + i)*260 + pw*3)*64 + c;
        #pragma unroll
        for (int j = 0; j < 3; ++j) {
            float v = fmaf(bits_to_f32(h2[rbase + (size_t)j*64]), a, bc);
            m = fmaxf(m, v);
        }
    }
    out[idx] = m;
}

extern "C" void kernel_launch(void* const* d_in, const int* in_sizes, int n_in,
                              void* d_out, int out_size, void* d_ws, size_t ws_size,
                              hipStream_t stream) {
    const float* x   = (const float*)d_in[0];
    const float* w1  = (const float*)d_in[1];
    const float* b1  = (const float*)d_in[2];
    const float* a1h = (const float*)d_in[3];
    const float* a1w = (const float*)d_in[4];
    const float* g1  = (const float*)d_in[5];
    const float* be1 = (const float*)d_in[6];
    const float* w2  = (const float*)d_in[7];
    const float* b2  = (const float*)d_in[8];
    const float* a2h = (const float*)d_in[9];
    const float* a2w = (const float*)d_in[10];
    const float* g2  = (const float*)d_in[11];
    const float* be2 = (const float*)d_in[12];
    float* out = (float*)d_out;

    char* ws = (char*)d_ws;
    float* stats = (float*)ws;                    // 512 floats
    float* sum1 = stats;       float* sq1 = stats + 64;
    float* A1   = stats + 128; float* Bc1 = stats + 192;
    float* sum2 = stats + 256; float* sq2 = stats + 320;
    float* A2   = stats + 384; float* Bc2 = stats + 448;
    float* cw1v = (float*)(ws + 2048);            // 4*NV1
    float* cw2v = cw1v + 4*NV1;                   // 4*NV2
    short* Apk1 = (short*)(cw2v + 4*NV2);         // 9*1024*8  = 73728
    short* Apk2 = Apk1 + 73728;                   // 18*1024*8 = 147456
    short* h1pad = Apk2 + 147456;                 // 16*134*262*64 = 35,950,592 (+4096 tail)
    short* xpad  = h1pad + (size_t)16*H1_PLANE*64 + 4096;
    short* h2    = xpad;                          // overlap: xpad dead before conv2 writes h2
    // footprint ≈ 143.7 MB

    // init
    zero_f_kernel<<<2, 256, 0, stream>>>(stats, 512);
    {
        long n4 = ((size_t)16*H1_PLANE*64 + 4096) * 2 / 16;
        zero4_kernel<<<4096, 256, 0, stream>>>((uint4*)h1pad, n4);
    }
    cwv_kernel<<<(NV1+255)/256, 256, 0, stream>>>(a1h, a1w, cw1v, NV1, 260, 130, 258);
    cwv_kernel<<<(NV2+255)/256, 256, 0, stream>>>(a2h, a2w, cw2v, NV2, 262, 132, 260);
    pack_kernel<32, 9><<<(9*1024+255)/256, 256, 0, stream>>>(w1, Apk1);
    pack_kernel<64,18><<<(18*1024+255)/256, 256, 0, stream>>>(w2, Apk2);
    xpad_kernel<<<16*132, 256, 0, stream>>>(x, xpad);

    // layer 1
    lrlc_conv<32, 9><<<dim3((NV1+63)/64, 16), 256, 0, stream>>>(
        xpad, Apk1, cw1v, b1, h1pad,
        /*Wv*/260, /*Hout*/130, /*Wreal*/258, /*Nv*/NV1, /*inPlanePos*/XPAD_PLANE,
        /*outW*/262, /*outPlanePos*/H1_PLANE, /*outPad*/2);
    stats_nhwc<<<256, 256, 0, stream>>>(h1pad, sum1, sq1, NPOS1, 258, 130, 262, H1_PLANE, 2);
    finalize_kernel<<<1, 64, 0, stream>>>(sum1, sq1, g1, be1, A1, Bc1, (float)NPOS1);
    bnrelu_nhwc<<<((long)NPOS1*16 + 255)/256, 256, 0, stream>>>(h1pad, A1, Bc1, NPOS1, 258, 130, 262, H1_PLANE, 2);

    // layer 2
    lrlc_conv<64,18><<<dim3((NV2+63)/64, 16), 256, 0, stream>>>(
        h1pad, Apk2, cw2v, b2, h2,
        /*Wv*/262, /*Hout*/132, /*Wreal*/260, /*Nv*/NV2, /*inPlanePos*/H1_PLANE,
        /*outW*/260, /*outPlanePos*/H2_PLANE, /*outPad*/0);
    stats_nhwc<<<256, 256, 0, stream>>>(h2, sum2, sq2, NPOS2, 260, 132, 260, H2_PLANE, 0);
    finalize_kernel<<<1, 64, 0, stream>>>(sum2, sq2, g2, be2, A2, Bc2, (float)NPOS2);

    maxpool_nhwc<<<(16*64*44*86 + 255)/256, 256, 0, stream>>>(h2, A2, Bc2, out);
}

// Round 4
// 1185.783 us; speedup vs baseline: 9.2203x; 1.1374x over previous
//
#include <hip/hip_runtime.h>
#include <hip/hip_bf16.h>
#include <math.h>

#define COUT 64
#define EPS  1e-5f

typedef __hip_bfloat16 bf16;
typedef short  short8  __attribute__((ext_vector_type(8)));
typedef short  short4v __attribute__((ext_vector_type(4)));
typedef float  floatx4 __attribute__((ext_vector_type(4)));

__device__ __forceinline__ short bf16_bits(float f) {
    union { __hip_bfloat16 h; short s; } u;
    u.h = __float2bfloat16(f);
    return u.s;
}
__device__ __forceinline__ float bits_to_f32(short s) {
    union { __hip_bfloat16 h; short s; } u;
    u.s = s;
    return __bfloat162float(u.h);
}

// ---------------- geometry ----------------
#define NV1   33800                /* virtual out plane conv1: 130 x 260 */
#define NV2   34584                /* virtual out plane conv2: 132 x 262 */
#define XPAD_PLANE  (132*260)
#define H1_PLANE    (134*262)
#define H2_PLANE    (132*260)
#define NPOS1 (16*130*258)
#define NPOS2 (16*132*260)

// ---------------- tiny utils ----------------
__global__ void zero_f_kernel(float* __restrict__ p, int n) {
    int i = blockIdx.x*blockDim.x + threadIdx.x;
    if (i < n) p[i] = 0.f;
}
__global__ void zero4_kernel(uint4* __restrict__ p, long n4) {
    long i = (long)blockIdx.x*blockDim.x + threadIdx.x;
    for (; i < n4; i += (long)gridDim.x*blockDim.x) p[i] = make_uint4(0,0,0,0);
}

__global__ void cwv_kernel(const float* __restrict__ ah, const float* __restrict__ aw,
                           float* __restrict__ cwv, int Nv, int Wv, int Lh, int Lw) {
    int idx = blockIdx.x*blockDim.x + threadIdx.x;
    if (idx >= Nv) return;
    int oh = idx / Wv, ow = idx - oh*Wv;
    if (ow > Lw-1) ow = Lw-1;
    float v0 = ah[0*Lh+oh] + aw[0*Lw+ow];
    float v1 = ah[1*Lh+oh] + aw[1*Lw+ow];
    float v2 = ah[2*Lh+oh] + aw[2*Lw+ow];
    float v3 = ah[3*Lh+oh] + aw[3*Lw+ow];
    float m = fmaxf(fmaxf(v0,v1), fmaxf(v2,v3));
    v0 = __expf(v0-m); v1 = __expf(v1-m); v2 = __expf(v2-m); v3 = __expf(v3-m);
    float inv = 1.f/(v0+v1+v2+v3);
    cwv[0*(size_t)Nv+idx] = v0*inv; cwv[1*(size_t)Nv+idx] = v1*inv;
    cwv[2*(size_t)Nv+idx] = v2*inv; cwv[3*(size_t)Nv+idx] = v3*inv;
}

// pack weights [4][64][CIN][3][3] fp32 -> fragment-major bf16:
// Apk[((s*16+t)*64+l)*8+j] = A[m=t*16+(l&15)][k=s*32+(l>>4)*8+j], k = tap*CIN + ci
template<int CIN_, int NSLICES>
__global__ void pack_kernel(const float* __restrict__ w, short* __restrict__ Apk) {
    int gid = blockIdx.x*256 + threadIdx.x;
    if (gid >= NSLICES*1024) return;
    int l = gid & 63, t = (gid >> 6) & 15, s = gid >> 10;
    int m = t*16 + (l & 15);
    int r = m >> 6, co = m & 63;
    int kbase = s*32 + ((l >> 4) << 3);
    short8 v;
    #pragma unroll
    for (int j = 0; j < 8; ++j) {
        int k = kbase + j;
        int tap = k / CIN_, ci = k % CIN_;
        v[j] = bf16_bits(w[(((size_t)(r*COUT + co))*CIN_ + ci)*9 + tap]);
    }
    *reinterpret_cast<short8*>(Apk + (size_t)gid*8) = v;
}

// x fp32 NCHW -> xpad bf16 NHWC [16][132][260][32], zero pads.
__global__ void xpad_kernel(const float* __restrict__ x, short* __restrict__ xp) {
    int row = blockIdx.x;                 // b*132 + ih
    int b = row / 132, ih = row - b*132;
    int ci = threadIdx.x & 31, iw0 = threadIdx.x >> 5;
    for (int iw = iw0; iw < 260; iw += 8) {
        float v = 0.f;
        if (ih >= 2 && ih < 130 && iw >= 2 && iw < 258)
            v = x[(((size_t)b*32 + ci)*128 + (ih-2))*256 + (iw-2)];
        xp[((size_t)row*260 + iw)*32 + ci] = bf16_bits(v);
    }
}

// ---------------- MFMA implicit-GEMM LRLC conv, N-tile=128, fused BN stats ----
// block: 256 thr = 4 waves. M=256 (4 ranks x 64 co), N=128 virtual positions.
// wave w owns m-tiles {i*4+w}: frag-row i == rank i, co in [w*16, w*16+16).
template<int CIN_, int NSLICES>
__launch_bounds__(256, 2)
__global__ void lrlc_conv(const short* __restrict__ Bpl, const short* __restrict__ Apk,
                          const float* __restrict__ cwv, const float* __restrict__ bias,
                          short* __restrict__ Out, float* __restrict__ sum, float* __restrict__ sq,
                          int Wv, int Hout, int Wreal, int Nv, int inPlanePos,
                          int outW, int outPlanePos, int outPad) {
    const int tid  = threadIdx.x;
    const int w    = tid >> 6, l = tid & 63;
    const int quad = l >> 4, l15 = l & 15;
    const int b    = blockIdx.y;
    const int n0   = blockIdx.x * 128;

    __shared__ float cwS[4*128];
    for (int t = tid; t < 512; t += 256) {
        int r = t >> 7, nn = t & 127;
        int n = n0 + nn; if (n > Nv-1) n = Nv-1;
        cwS[t] = cwv[(size_t)r*Nv + n];
    }
    __syncthreads();

    const short* Bb = Bpl + (size_t)b*inPlanePos*CIN_;
    int bOff[8];
    #pragma unroll
    for (int j = 0; j < 8; ++j) bOff[j] = (n0 + j*16 + l15)*CIN_ + quad*8;
    const short* Aw = Apk + (size_t)(w*64 + l)*8;

    floatx4 acc[4][8];
    #pragma unroll
    for (int i = 0; i < 4; ++i)
        #pragma unroll
        for (int j = 0; j < 8; ++j)
            acc[i][j] = (floatx4){0.f,0.f,0.f,0.f};

    #pragma unroll
    for (int s = 0; s < NSLICES; ++s) {
        const int tap = (CIN_ == 32) ? s : (s >> 1);
        const int cb  = (CIN_ == 32) ? 0 : ((s & 1) << 5);
        const int koff = ((tap/3)*Wv + (tap%3))*CIN_ + cb;
        short8 bfr[8], afr[4];
        #pragma unroll
        for (int j = 0; j < 8; ++j)
            bfr[j] = *reinterpret_cast<const short8*>(Bb + bOff[j] + koff);
        #pragma unroll
        for (int i = 0; i < 4; ++i)
            afr[i] = *reinterpret_cast<const short8*>(Aw + (size_t)(s*16 + i*4)*512);
        #pragma unroll
        for (int i = 0; i < 4; ++i)
            #pragma unroll
            for (int j = 0; j < 8; ++j)
                acc[i][j] = __builtin_amdgcn_mfma_f32_16x16x32_bf16(afr[i], bfr[j], acc[i][j], 0, 0, 0);
    }

    // epilogue: rank-combine, +bias, store, accumulate BN stats (fp32, pre-round)
    const int co_base = w*16 + quad*4;
    float bs[4];
    #pragma unroll
    for (int rg = 0; rg < 4; ++rg) bs[rg] = bias[co_base + rg];
    float st[4] = {0.f,0.f,0.f,0.f}, st2[4] = {0.f,0.f,0.f,0.f};
    #pragma unroll
    for (int j = 0; j < 8; ++j) {
        int nl = j*16 + l15;
        int n  = n0 + nl;
        int oh = n / Wv, ow = n - oh*Wv;
        bool valid = (ow < Wreal) && (oh < Hout);
        float c0 = cwS[nl], c1 = cwS[128+nl], c2 = cwS[256+nl], c3 = cwS[384+nl];
        short4v pk;
        #pragma unroll
        for (int rg = 0; rg < 4; ++rg) {
            float v = acc[0][j][rg]*c0 + acc[1][j][rg]*c1
                    + acc[2][j][rg]*c2 + acc[3][j][rg]*c3 + bs[rg];
            if (valid) { st[rg] += v; st2[rg] = fmaf(v, v, st2[rg]); }
            pk[rg] = bf16_bits(v);
        }
        if (valid) {
            size_t op = ((size_t)b*outPlanePos + (size_t)(oh + outPad)*outW + (ow + outPad))*(size_t)COUT + co_base;
            *reinterpret_cast<short4v*>(Out + op) = pk;
        }
    }
    // 16-lane (l15) butterfly: channel c = co_base+rg is shared by 16 consecutive lanes
    #pragma unroll
    for (int m = 1; m < 16; m <<= 1) {
        #pragma unroll
        for (int rg = 0; rg < 4; ++rg) {
            st[rg]  += __shfl_xor(st[rg],  m, 16);
            st2[rg] += __shfl_xor(st2[rg], m, 16);
        }
    }
    if (l15 == 0) {
        #pragma unroll
        for (int rg = 0; rg < 4; ++rg) {
            atomicAdd(&sum[co_base+rg], st[rg]);
            atomicAdd(&sq[co_base+rg],  st2[rg]);
        }
    }
}

__global__ void finalize_kernel(const float* __restrict__ sum, const float* __restrict__ sumsq,
                                const float* __restrict__ g, const float* __restrict__ be,
                                float* __restrict__ A, float* __restrict__ Bc, float cnt) {
    int c = threadIdx.x;
    if (c >= COUT) return;
    float mean = sum[c]/cnt;
    float var  = sumsq[c]/cnt - mean*mean;
    float inv  = rsqrtf(var + EPS);
    float a = g[c]*inv;
    A[c]  = a;
    Bc[c] = fmaf(-mean, a, be[c]);
}

// row-based in-place BN+ReLU on h1pad interior; grid 16*130, block 256, 16B vec
__global__ void bnrelu_rows(short* __restrict__ h, const float* __restrict__ A,
                            const float* __restrict__ Bc) {
    __shared__ float sA[64], sB[64];
    if (threadIdx.x < 64) { sA[threadIdx.x] = A[threadIdx.x]; sB[threadIdx.x] = Bc[threadIdx.x]; }
    __syncthreads();
    int row = blockIdx.x;                 // b*130 + oh
    int b = row / 130, oh = row - b*130;
    short* base = h + ((size_t)(b*134 + oh + 2)*262 + 2)*64;
    const int nvec = 258*64/8;            // 2064
    for (int it = threadIdx.x; it < nvec; it += 256) {
        short8 d = *reinterpret_cast<short8*>(base + it*8);
        int c0 = (it*8) & 63;
        #pragma unroll
        for (int q = 0; q < 8; ++q) {
            float v = bits_to_f32(d[q]);
            int c = c0 + q;
            v = fmaxf(fmaf(v, sA[c], sB[c]), 0.f);
            d[q] = bf16_bits(v);
        }
        *reinterpret_cast<short8*>(base + it*8) = d;
    }
}

// fused BN2+ReLU+3x3/3 maxpool: h2 NHWC -> out fp32 NCHW [16,64,44,86]
// grid 16*44 (one block per output row), block 256, 8B vec loads
__global__ void maxpool_rows(const short* __restrict__ h2, const float* __restrict__ A,
                             const float* __restrict__ Bc, float* __restrict__ out) {
    __shared__ float sA[64], sB[64];
    if (threadIdx.x < 64) { sA[threadIdx.x] = A[threadIdx.x]; sB[threadIdx.x] = Bc[threadIdx.x]; }
    __syncthreads();
    int row = blockIdx.x;                 // b*44 + ph
    int b = row / 44, ph = row - b*44;
    for (int item = threadIdx.x; item < 86*16; item += 256) {
        int cg = item & 15, pw = item >> 4;
        float m[4] = {0.f,0.f,0.f,0.f};   // ReLU floor
        #pragma unroll
        for (int i = 0; i < 3; ++i) {
            const short* rp = h2 + ((size_t)(b*132 + ph*3 + i)*260 + pw*3)*64 + cg*4;
            #pragma unroll
            for (int j = 0; j < 3; ++j) {
                short4v d = *reinterpret_cast<const short4v*>(rp + j*64);
                #pragma unroll
                for (int q = 0; q < 4; ++q) {
                    int c = cg*4 + q;
                    float v = fmaf(bits_to_f32(d[q]), sA[c], sB[c]);
                    m[q] = fmaxf(m[q], v);
                }
            }
        }
        #pragma unroll
        for (int q = 0; q < 4; ++q)
            out[((size_t)(b*64 + cg*4 + q)*44 + ph)*86 + pw] = m[q];
    }
}

extern "C" void kernel_launch(void* const* d_in, const int* in_sizes, int n_in,
                              void* d_out, int out_size, void* d_ws, size_t ws_size,
                              hipStream_t stream) {
    const float* x   = (const float*)d_in[0];
    const float* w1  = (const float*)d_in[1];
    const float* b1  = (const float*)d_in[2];
    const float* a1h = (const float*)d_in[3];
    const float* a1w = (const float*)d_in[4];
    const float* g1  = (const float*)d_in[5];
    const float* be1 = (const float*)d_in[6];
    const float* w2  = (const float*)d_in[7];
    const float* b2  = (const float*)d_in[8];
    const float* a2h = (const float*)d_in[9];
    const float* a2w = (const float*)d_in[10];
    const float* g2  = (const float*)d_in[11];
    const float* be2 = (const float*)d_in[12];
    float* out = (float*)d_out;

    char* ws = (char*)d_ws;
    float* stats = (float*)ws;                    // 512 floats
    float* sum1 = stats;       float* sq1 = stats + 64;
    float* A1   = stats + 128; float* Bc1 = stats + 192;
    float* sum2 = stats + 256; float* sq2 = stats + 320;
    float* A2   = stats + 384; float* Bc2 = stats + 448;
    float* cw1v = (float*)(ws + 2048);
    float* cw2v = cw1v + 4*NV1;
    short* Apk1 = (short*)(cw2v + 4*NV2);         // 73728 shorts
    short* Apk2 = Apk1 + 73728;                   // 147456 shorts
    short* h1pad = Apk2 + 147456;                 // 16*134*262*64 shorts
    short* xpad  = h1pad + (size_t)16*H1_PLANE*64 + 4096;
    short* h2    = xpad;                          // xpad dead before conv2 writes h2

    zero_f_kernel<<<2, 256, 0, stream>>>(stats, 512);
    {
        long n4 = ((size_t)16*H1_PLANE*64 + 4096) * 2 / 16;
        zero4_kernel<<<4096, 256, 0, stream>>>((uint4*)h1pad, n4);
    }
    cwv_kernel<<<(NV1+255)/256, 256, 0, stream>>>(a1h, a1w, cw1v, NV1, 260, 130, 258);
    cwv_kernel<<<(NV2+255)/256, 256, 0, stream>>>(a2h, a2w, cw2v, NV2, 262, 132, 260);
    pack_kernel<32, 9><<<(9*1024+255)/256, 256, 0, stream>>>(w1, Apk1);
    pack_kernel<64,18><<<(18*1024+255)/256, 256, 0, stream>>>(w2, Apk2);
    xpad_kernel<<<16*132, 256, 0, stream>>>(x, xpad);

    // layer 1 (stats fused)
    lrlc_conv<32, 9><<<dim3((NV1+127)/128, 16), 256, 0, stream>>>(
        xpad, Apk1, cw1v, b1, h1pad, sum1, sq1,
        260, 130, 258, NV1, XPAD_PLANE, 262, H1_PLANE, 2);
    finalize_kernel<<<1, 64, 0, stream>>>(sum1, sq1, g1, be1, A1, Bc1, (float)NPOS1);
    bnrelu_rows<<<16*130, 256, 0, stream>>>(h1pad, A1, Bc1);

    // layer 2 (stats fused)
    lrlc_conv<64,18><<<dim3((NV2+127)/128, 16), 256, 0, stream>>>(
        h1pad, Apk2, cw2v, b2, h2, sum2, sq2,
        262, 132, 260, NV2, H1_PLANE, 260, H2_PLANE, 0);
    finalize_kernel<<<1, 64, 0, stream>>>(sum2, sq2, g2, be2, A2, Bc2, (float)NPOS2);

    maxpool_rows<<<16*44, 256, 0, stream>>>(h2, A2, Bc2, out);
}